// Round 2
// baseline (15417.174 us; speedup 1.0000x reference)
//
#include <hip/hip_runtime.h>
#include <hip/hip_bf16.h>

#define BB 32
#define SS 128
#define CC 128
#define HH 128
#define OO 64
// gates = 3*HH = 384; 2 threads per gate row -> 768 threads (12 waves)

__device__ __forceinline__ float sigmoidf_(float x) {
    return 1.0f / (1.0f + __expf(-x));
}
__device__ __forceinline__ float tanh_fast_(float x) {
    // tanh(x) = 1 - 2/(exp(2x)+1); pre-activation range here is small, no overflow
    return 1.0f - 2.0f / (__expf(2.0f * x) + 1.0f);
}

// One workgroup per (direction, batch): runs the full 16384-step chain.
// Thread pair (2g, 2g+1) owns gate row g; each thread holds 64 f32 weights in
// NAMED float4 registers (no array -> no scratch). Halves combined via
// __shfl_xor(.,1). h double-buffered in LDS; x[b] slice staged in LDS (64KB).
__global__ __launch_bounds__(768, 3) void gru_chain_kernel(
    const float* __restrict__ x,       // (B,S,C)
    const float* __restrict__ h_prev,  // (2,B,H)
    const float* __restrict__ Wih_f, const float* __restrict__ Whh_f,
    const float* __restrict__ bih_f, const float* __restrict__ bhh_f,
    const float* __restrict__ Wih_b, const float* __restrict__ Whh_b,
    const float* __restrict__ bih_b, const float* __restrict__ bhh_b,
    float* __restrict__ hsnap)         // (2, C, B, H) column-end snapshots
{
    const int wg   = blockIdx.x;
    const int d    = wg >> 5;        // 0 = forward, 1 = backward
    const int b    = wg & 31;
    const int t    = threadIdx.x;    // 0..767
    const int g    = t >> 1;         // gate row 0..383
    const int half = t & 1;          // which 64-wide half of the dot

    const float* __restrict__ Wih = d ? Wih_b : Wih_f;
    const float* __restrict__ Whh = d ? Whh_b : Whh_f;
    const float* __restrict__ bih = d ? bih_b : bih_f;
    const float* __restrict__ bhh = d ? bhh_b : bhh_f;

    __shared__ float xs[SS * CC];      // 64KB, x[b] slice
    __shared__ float hbuf[2][HH];      // double-buffered hidden state
    __shared__ float gate[2 * HH];     // r in [0,H), z in [H,2H)

    // stage x[b] (contiguous 16384 floats) into LDS, coalesced float4
    {
        const float4* xb4 = reinterpret_cast<const float4*>(x + (size_t)b * SS * CC);
        float4* xs4 = reinterpret_cast<float4*>(xs);
        for (int i = t; i < SS * CC / 4; i += 768) xs4[i] = xb4[i];
    }

    // 16 NAMED float4 weight registers (64 VGPRs) — no array, nothing to spill
    const float4* wr = reinterpret_cast<const float4*>(Whh + g * HH + half * 64);
#define LOADW(i) const float4 w##i = wr[i];
    LOADW(0)  LOADW(1)  LOADW(2)  LOADW(3)
    LOADW(4)  LOADW(5)  LOADW(6)  LOADW(7)
    LOADW(8)  LOADW(9)  LOADW(10) LOADW(11)
    LOADW(12) LOADW(13) LOADW(14) LOADW(15)
#undef LOADW

    const float wih_t = Wih[g];
    const float bih_t = bih[g];
    const float bhh_t = bhh[g];

    if (t < HH) hbuf[0][t] = h_prev[(d * BB + b) * HH + t];
    __syncthreads();

    int p = 0;
    for (int s = 0; s < SS * CC; ++s) {
        const int c  = s >> 7;                   // column index
        const int ts = s & (SS - 1);             // step within column
        const int tt = d ? (SS - 1 - ts) : ts;   // backward reads reversed rows
        const float xv = xs[tt * CC + c];        // broadcast LDS read

        // partial dot over this thread's 64 weights; 4 accumulators
        const float4* h4 = reinterpret_cast<const float4*>(hbuf[p]) + half * 16;
        float a0 = 0.f, a1 = 0.f, a2 = 0.f, a3 = 0.f;
#define MAC(i) { const float4 hv = h4[i]; \
        a0 = fmaf(w##i.x, hv.x, a0); a1 = fmaf(w##i.y, hv.y, a1); \
        a2 = fmaf(w##i.z, hv.z, a2); a3 = fmaf(w##i.w, hv.w, a3); }
        MAC(0)  MAC(1)  MAC(2)  MAC(3)
        MAC(4)  MAC(5)  MAC(6)  MAC(7)
        MAC(8)  MAC(9)  MAC(10) MAC(11)
        MAC(12) MAC(13) MAC(14) MAC(15)
#undef MAC
        float part = (a0 + a1) + (a2 + a3);
        part += __shfl_xor(part, 1);             // combine the two halves
        const float gh = part + bhh_t;
        const float gi = fmaf(xv, wih_t, bih_t);

        if (g < 2 * HH) {                        // r and z gate rows (wave-uniform)
            const float rz = sigmoidf_(gi + gh);
            if (half == 0) gate[g] = rz;
        }
        __syncthreads();                         // barrier A: r,z ready
        if (g >= 2 * HH) {                       // n gate rows (wave-uniform)
            const int j = g - 2 * HH;
            const float r  = gate[j];
            const float z  = gate[HH + j];
            const float n  = tanh_fast_(fmaf(r, gh, gi)); // tanh(inn + r*hn)
            const float hp = hbuf[p][j];
            const float hn = fmaf(z, hp - n, n);          // (1-z)*n + z*h
            if (half == 0) {
                hbuf[p ^ 1][j] = hn;
                if (ts == SS - 1) {
                    hsnap[(((size_t)d * CC + c) * BB + b) * HH + j] = hn;
                }
            }
        }
        __syncthreads();                         // barrier B: h' ready
        p ^= 1;
    }
}

// One block (= one wave of 64 threads) per (c,b): FC + ReLU + softmax over O=64.
__global__ __launch_bounds__(64) void fc_softmax_kernel(
    const float* __restrict__ hsnap,   // (2, C, B, H)
    const float* __restrict__ W_fc,    // (O, 2H)
    const float* __restrict__ b_fc,    // (O,)
    float* __restrict__ out)           // (B, C, O)
{
    const int cb = blockIdx.x;         // c * B + b
    const int c  = cb >> 5;
    const int b  = cb & 31;
    const int o  = threadIdx.x;        // 0..63

    __shared__ float feat[2 * HH];     // [hf, hb]
    #pragma unroll
    for (int i = 0; i < 4; ++i) {
        const int idx = i * 64 + o;            // 0..255
        const int dd  = idx >> 7;              // 0: hf, 1: hb
        const int j   = idx & (HH - 1);
        feat[idx] = hsnap[(((size_t)dd * CC + c) * BB + b) * HH + j];
    }
    __syncthreads();

    float acc = 0.f;
    const float4* wrow = reinterpret_cast<const float4*>(W_fc + o * 2 * HH);
    const float4* f4   = reinterpret_cast<const float4*>(feat);
    #pragma unroll
    for (int k = 0; k < 64; ++k) {
        const float4 wv = wrow[k];
        const float4 fv = f4[k];
        acc = fmaf(wv.x, fv.x, acc);
        acc = fmaf(wv.y, fv.y, acc);
        acc = fmaf(wv.z, fv.z, acc);
        acc = fmaf(wv.w, fv.w, acc);
    }
    float v = fmaxf(acc + b_fc[o], 0.0f);

    // softmax across the 64-lane wave
    float m = v;
    #pragma unroll
    for (int off = 32; off; off >>= 1) m = fmaxf(m, __shfl_xor(m, off));
    const float e = __expf(v - m);
    float ssum = e;
    #pragma unroll
    for (int off = 32; off; off >>= 1) ssum += __shfl_xor(ssum, off);

    out[((size_t)b * CC + c) * OO + o] = e / ssum;
}

extern "C" void kernel_launch(void* const* d_in, const int* in_sizes, int n_in,
                              void* d_out, int out_size, void* d_ws, size_t ws_size,
                              hipStream_t stream) {
    const float* x      = (const float*)d_in[0];
    const float* h_prev = (const float*)d_in[1];
    const float* Wih_f  = (const float*)d_in[2];
    const float* Whh_f  = (const float*)d_in[3];
    const float* bih_f  = (const float*)d_in[4];
    const float* bhh_f  = (const float*)d_in[5];
    const float* Wih_b  = (const float*)d_in[6];
    const float* Whh_b  = (const float*)d_in[7];
    const float* bih_b  = (const float*)d_in[8];
    const float* bhh_b  = (const float*)d_in[9];
    const float* W_fc   = (const float*)d_in[10];
    const float* b_fc   = (const float*)d_in[11];
    float* out   = (float*)d_out;
    float* hsnap = (float*)d_ws;   // needs 2*C*B*H*4 = 4 MiB of scratch

    gru_chain_kernel<<<64, 768, 0, stream>>>(x, h_prev, Wih_f, Whh_f, bih_f, bhh_f,
                                             Wih_b, Whh_b, bih_b, bhh_b, hsnap);
    fc_softmax_kernel<<<CC * BB, 64, 0, stream>>>(hsnap, W_fc, b_fc, out);
}

// Round 3
// 13016.678 us; speedup vs baseline: 1.1844x; 1.1844x over previous
//
#include <hip/hip_runtime.h>
#include <hip/hip_bf16.h>

#define BB 32
#define SS 128
#define CC 128
#define HH 128
#define OO 64

typedef float vf4 __attribute__((ext_vector_type(4)));

__device__ __forceinline__ float sigmoidf_(float x) {
    return 1.0f / (1.0f + __expf(-x));
}
__device__ __forceinline__ float tanh_fast_(float x) {
    return 1.0f - 2.0f / (__expf(2.0f * x) + 1.0f);  // |x| small here, no overflow
}

// One workgroup per (direction, batch). 256 threads = 4 waves.
// Thread (j = t>>1, half = t&1) computes gate rows j (r), j+128 (z), j+256 (n)
// over 64 of the 128 dot elements; halves combined with __shfl_xor(.,1).
// r,z,n are LOCAL to the pair -> single barrier per step, no gate[] buffer.
// Weights: 48 named vf4 (192 VGPRs) pinned via empty asm so the compiler
// cannot rematerialize the global loads inside the loop (round-2 failure).
// h in LDS with halves at float-offset 0 / 80 so the wave's two broadcast
// addresses hit disjoint banks (round-2's 8e8 bank conflicts).
__global__ __launch_bounds__(256, 1) void gru_chain_kernel(
    const float* __restrict__ x,       // (B,S,C)
    const float* __restrict__ h_prev,  // (2,B,H)
    const float* __restrict__ Wih_f, const float* __restrict__ Whh_f,
    const float* __restrict__ bih_f, const float* __restrict__ bhh_f,
    const float* __restrict__ Wih_b, const float* __restrict__ Whh_b,
    const float* __restrict__ bih_b, const float* __restrict__ bhh_b,
    float* __restrict__ hsnap)         // (2, C, B, H) column-end snapshots
{
    const int wg   = blockIdx.x;
    const int d    = wg >> 5;        // 0 = forward, 1 = backward
    const int b    = wg & 31;
    const int t    = threadIdx.x;    // 0..255
    const int j    = t >> 1;         // hidden index 0..127
    const int half = t & 1;          // which 64-wide half of the dot

    const float* __restrict__ Wih = d ? Wih_b : Wih_f;
    const float* __restrict__ Whh = d ? Whh_b : Whh_f;
    const float* __restrict__ bih = d ? bih_b : bih_f;
    const float* __restrict__ bhh = d ? bhh_b : bhh_f;

    __shared__ float xs[SS * CC];      // 64KB, x[b] slice (S,C) layout
    __shared__ float hbuf[2][144];     // h: elem e at (e<64 ? e : e+16) — bank skew

    // stage x[b] (16384 contiguous floats) into LDS, coalesced float4
    {
        const float4* xb4 = reinterpret_cast<const float4*>(x + (size_t)b * SS * CC);
        float4* xs4 = reinterpret_cast<float4*>(xs);
        #pragma unroll
        for (int i = 0; i < 16; ++i) xs4[t + i * 256] = xb4[t + i * 256];
    }

    // 48 NAMED vf4 weight registers (192 VGPRs): rows j, j+128, j+256, this half
    const vf4* wr_r = reinterpret_cast<const vf4*>(Whh + (j          ) * HH + half * 64);
    const vf4* wr_z = reinterpret_cast<const vf4*>(Whh + (j +     HH ) * HH + half * 64);
    const vf4* wr_n = reinterpret_cast<const vf4*>(Whh + (j + 2 * HH ) * HH + half * 64);
#define LW(p, i) vf4 w##p##i = wr_##p[i];
    LW(r,0) LW(r,1) LW(r,2) LW(r,3) LW(r,4) LW(r,5) LW(r,6) LW(r,7)
    LW(r,8) LW(r,9) LW(r,10) LW(r,11) LW(r,12) LW(r,13) LW(r,14) LW(r,15)
    LW(z,0) LW(z,1) LW(z,2) LW(z,3) LW(z,4) LW(z,5) LW(z,6) LW(z,7)
    LW(z,8) LW(z,9) LW(z,10) LW(z,11) LW(z,12) LW(z,13) LW(z,14) LW(z,15)
    LW(n,0) LW(n,1) LW(n,2) LW(n,3) LW(n,4) LW(n,5) LW(n,6) LW(n,7)
    LW(n,8) LW(n,9) LW(n,10) LW(n,11) LW(n,12) LW(n,13) LW(n,14) LW(n,15)
#undef LW
    // pin: values become opaque -> rematerialization from Whh is illegal
    asm volatile("" : "+v"(wr0), "+v"(wr1), "+v"(wr2), "+v"(wr3),
                      "+v"(wr4), "+v"(wr5), "+v"(wr6), "+v"(wr7),
                      "+v"(wr8), "+v"(wr9), "+v"(wr10), "+v"(wr11),
                      "+v"(wr12), "+v"(wr13), "+v"(wr14), "+v"(wr15));
    asm volatile("" : "+v"(wz0), "+v"(wz1), "+v"(wz2), "+v"(wz3),
                      "+v"(wz4), "+v"(wz5), "+v"(wz6), "+v"(wz7),
                      "+v"(wz8), "+v"(wz9), "+v"(wz10), "+v"(wz11),
                      "+v"(wz12), "+v"(wz13), "+v"(wz14), "+v"(wz15));
    asm volatile("" : "+v"(wn0), "+v"(wn1), "+v"(wn2), "+v"(wn3),
                      "+v"(wn4), "+v"(wn5), "+v"(wn6), "+v"(wn7),
                      "+v"(wn8), "+v"(wn9), "+v"(wn10), "+v"(wn11),
                      "+v"(wn12), "+v"(wn13), "+v"(wn14), "+v"(wn15));

    const float wih_r = Wih[j];           const float bih_r = bih[j];
    const float wih_z = Wih[j + HH];      const float bih_z = bih[j + HH];
    const float wih_n = Wih[j + 2 * HH];  const float bih_n = bih[j + 2 * HH];
    const float bhh_r = bhh[j];
    const float bhh_z = bhh[j + HH];
    const float bhh_n = bhh[j + 2 * HH];

    float hp = h_prev[(d * BB + b) * HH + j];   // own h, carried in register
    if (half == 0) hbuf[0][(j < 64) ? j : j + 16] = hp;
    __syncthreads();

    int p = 0;
    for (int c = 0; c < CC; ++c) {
        for (int ts = 0; ts < SS; ++ts) {
            const int tt = d ? (SS - 1 - ts) : ts;
            const float xv = xs[tt * CC + c];   // all-lane broadcast read

            const vf4* h4 = reinterpret_cast<const vf4*>(hbuf[p]) + half * 20;
            float r0 = 0.f, r1 = 0.f, r2 = 0.f, r3 = 0.f;
            float z0 = 0.f, z1 = 0.f, z2 = 0.f, z3 = 0.f;
            float n0 = 0.f, n1 = 0.f, n2 = 0.f, n3 = 0.f;
#define MAC(i) { const vf4 hv = h4[i]; \
        r0 = fmaf(wr##i.x, hv.x, r0); r1 = fmaf(wr##i.y, hv.y, r1); \
        r2 = fmaf(wr##i.z, hv.z, r2); r3 = fmaf(wr##i.w, hv.w, r3); \
        z0 = fmaf(wz##i.x, hv.x, z0); z1 = fmaf(wz##i.y, hv.y, z1); \
        z2 = fmaf(wz##i.z, hv.z, z2); z3 = fmaf(wz##i.w, hv.w, z3); \
        n0 = fmaf(wn##i.x, hv.x, n0); n1 = fmaf(wn##i.y, hv.y, n1); \
        n2 = fmaf(wn##i.z, hv.z, n2); n3 = fmaf(wn##i.w, hv.w, n3); }
            MAC(0)  MAC(1)  MAC(2)  MAC(3)
            MAC(4)  MAC(5)  MAC(6)  MAC(7)
            MAC(8)  MAC(9)  MAC(10) MAC(11)
            MAC(12) MAC(13) MAC(14) MAC(15)
#undef MAC
            float sr = (r0 + r1) + (r2 + r3);
            float sz = (z0 + z1) + (z2 + z3);
            float sn = (n0 + n1) + (n2 + n3);
            sr += __shfl_xor(sr, 1);            // combine halves (same wave)
            sz += __shfl_xor(sz, 1);
            sn += __shfl_xor(sn, 1);

            const float gh_r = sr + bhh_r;
            const float gh_z = sz + bhh_z;
            const float gh_n = sn + bhh_n;
            const float gi_r = fmaf(xv, wih_r, bih_r);
            const float gi_z = fmaf(xv, wih_z, bih_z);
            const float gi_n = fmaf(xv, wih_n, bih_n);

            const float r = sigmoidf_(gi_r + gh_r);
            const float z = sigmoidf_(gi_z + gh_z);
            const float n = tanh_fast_(fmaf(r, gh_n, gi_n));
            const float hn = fmaf(z, hp - n, n);      // (1-z)*n + z*h
            hp = hn;                                  // both lanes keep it

            if (half == 0) hbuf[p ^ 1][(j < 64) ? j : j + 16] = hn;
            __syncthreads();                          // single barrier per step
            p ^= 1;
        }
        if (half == 0) {
            hsnap[(((size_t)d * CC + c) * BB + b) * HH + j] = hp;
        }
    }
}

// One block (= one wave of 64 threads) per (c,b): FC + ReLU + softmax over O=64.
__global__ __launch_bounds__(64) void fc_softmax_kernel(
    const float* __restrict__ hsnap,   // (2, C, B, H)
    const float* __restrict__ W_fc,    // (O, 2H)
    const float* __restrict__ b_fc,    // (O,)
    float* __restrict__ out)           // (B, C, O)
{
    const int cb = blockIdx.x;         // c * B + b
    const int c  = cb >> 5;
    const int b  = cb & 31;
    const int o  = threadIdx.x;        // 0..63

    __shared__ float feat[2 * HH];     // [hf, hb]
    #pragma unroll
    for (int i = 0; i < 4; ++i) {
        const int idx = i * 64 + o;            // 0..255
        const int dd  = idx >> 7;              // 0: hf, 1: hb
        const int jj  = idx & (HH - 1);
        feat[idx] = hsnap[(((size_t)dd * CC + c) * BB + b) * HH + jj];
    }
    __syncthreads();

    float acc = 0.f;
    const float4* wrow = reinterpret_cast<const float4*>(W_fc + o * 2 * HH);
    const float4* f4   = reinterpret_cast<const float4*>(feat);
    #pragma unroll
    for (int k = 0; k < 64; ++k) {
        const float4 wv = wrow[k];
        const float4 fv = f4[k];
        acc = fmaf(wv.x, fv.x, acc);
        acc = fmaf(wv.y, fv.y, acc);
        acc = fmaf(wv.z, fv.z, acc);
        acc = fmaf(wv.w, fv.w, acc);
    }
    float v = fmaxf(acc + b_fc[o], 0.0f);

    float m = v;
    #pragma unroll
    for (int off = 32; off; off >>= 1) m = fmaxf(m, __shfl_xor(m, off));
    const float e = __expf(v - m);
    float ssum = e;
    #pragma unroll
    for (int off = 32; off; off >>= 1) ssum += __shfl_xor(ssum, off);

    out[((size_t)b * CC + c) * OO + o] = e / ssum;
}

extern "C" void kernel_launch(void* const* d_in, const int* in_sizes, int n_in,
                              void* d_out, int out_size, void* d_ws, size_t ws_size,
                              hipStream_t stream) {
    const float* x      = (const float*)d_in[0];
    const float* h_prev = (const float*)d_in[1];
    const float* Wih_f  = (const float*)d_in[2];
    const float* Whh_f  = (const float*)d_in[3];
    const float* bih_f  = (const float*)d_in[4];
    const float* bhh_f  = (const float*)d_in[5];
    const float* Wih_b  = (const float*)d_in[6];
    const float* Whh_b  = (const float*)d_in[7];
    const float* bih_b  = (const float*)d_in[8];
    const float* bhh_b  = (const float*)d_in[9];
    const float* W_fc   = (const float*)d_in[10];
    const float* b_fc   = (const float*)d_in[11];
    float* out   = (float*)d_out;
    float* hsnap = (float*)d_ws;   // 2*C*B*H*4 = 4 MiB of scratch

    gru_chain_kernel<<<64, 256, 0, stream>>>(x, h_prev, Wih_f, Whh_f, bih_f, bhh_f,
                                             Wih_b, Whh_b, bih_b, bhh_b, hsnap);
    fc_softmax_kernel<<<CC * BB, 64, 0, stream>>>(hsnap, W_fc, b_fc, out);
}

// Round 4
// 10886.816 us; speedup vs baseline: 1.4161x; 1.1956x over previous
//
#include <hip/hip_runtime.h>
#include <hip/hip_bf16.h>

#define BB 32
#define SS 128
#define CC 128
#define HH 128
#define OO 64

typedef float vf4 __attribute__((ext_vector_type(4)));

__device__ __forceinline__ float sigmoidf_(float x) {
    return 1.0f / (1.0f + __expf(-x));
}
__device__ __forceinline__ float tanh_fast_(float x) {
    return 1.0f - 2.0f / (__expf(2.0f * x) + 1.0f);  // |x| small here, no overflow
}

// One workgroup per (direction, batch). 512 threads = 8 waves.
// Thread (j = t>>2, q = t&3) computes gate rows j (r), j+128 (z), j+256 (n)
// over quarter q (32 elements) of the 128-wide dot; quarters combined with
// __shfl_xor 1,2 (same wave: 4 consecutive lanes share j).
// Per-thread weights: 24 vf4 = 96 VGPRs -> fits a 2-waves/SIMD budget, so the
// allocator should keep them resident (rounds 2-3 failed at 192 VGPRs).
// vf4 elementwise fma -> v_pk_fma_f32 candidates (halves FMA issue).
// h in LDS with quarter q at float-offset q*36 (16B-aligned, banks 4q..4q+3)
// -> the wave's 4 broadcast addresses hit disjoint banks.
__global__ __launch_bounds__(512, 2) void gru_chain_kernel(
    const float* __restrict__ x,       // (B,S,C)
    const float* __restrict__ h_prev,  // (2,B,H)
    const float* __restrict__ Wih_f, const float* __restrict__ Whh_f,
    const float* __restrict__ bih_f, const float* __restrict__ bhh_f,
    const float* __restrict__ Wih_b, const float* __restrict__ Whh_b,
    const float* __restrict__ bih_b, const float* __restrict__ bhh_b,
    float* __restrict__ hsnap)         // (2, C, B, H) column-end snapshots
{
    const int wg = blockIdx.x;
    const int d  = wg >> 5;        // 0 = forward, 1 = backward
    const int b  = wg & 31;
    const int t  = threadIdx.x;    // 0..511
    const int j  = t >> 2;         // hidden index 0..127
    const int q  = t & 3;          // quarter of the dot

    const float* __restrict__ Wih = d ? Wih_b : Wih_f;
    const float* __restrict__ Whh = d ? Whh_b : Whh_f;
    const float* __restrict__ bih = d ? bih_b : bih_f;
    const float* __restrict__ bhh = d ? bhh_b : bhh_f;

    __shared__ float xs[SS * CC];      // 64KB, x[b] slice (S,C) layout
    __shared__ float hbuf[2][144];     // h[e] at e + (e>>5)*4  (quarter skew)

    // stage x[b] (16384 contiguous floats) into LDS, coalesced float4
    {
        const float4* xb4 = reinterpret_cast<const float4*>(x + (size_t)b * SS * CC);
        float4* xs4 = reinterpret_cast<float4*>(xs);
        #pragma unroll
        for (int i = 0; i < 8; ++i) xs4[t + i * 512] = xb4[t + i * 512];
    }

    // 24 NAMED vf4 weight registers (96 VGPRs): rows j, j+128, j+256, quarter q
    const vf4* wr_r = reinterpret_cast<const vf4*>(Whh + (j          ) * HH + q * 32);
    const vf4* wr_z = reinterpret_cast<const vf4*>(Whh + (j +     HH ) * HH + q * 32);
    const vf4* wr_n = reinterpret_cast<const vf4*>(Whh + (j + 2 * HH ) * HH + q * 32);
#define LW(p, i) vf4 w##p##i = wr_##p[i];
    LW(r,0) LW(r,1) LW(r,2) LW(r,3) LW(r,4) LW(r,5) LW(r,6) LW(r,7)
    LW(z,0) LW(z,1) LW(z,2) LW(z,3) LW(z,4) LW(z,5) LW(z,6) LW(z,7)
    LW(n,0) LW(n,1) LW(n,2) LW(n,3) LW(n,4) LW(n,5) LW(n,6) LW(n,7)
#undef LW
    // pin: asm results are opaque -> rematerialization from Whh is illegal
    asm volatile("" : "+v"(wr0), "+v"(wr1), "+v"(wr2), "+v"(wr3),
                      "+v"(wr4), "+v"(wr5), "+v"(wr6), "+v"(wr7));
    asm volatile("" : "+v"(wz0), "+v"(wz1), "+v"(wz2), "+v"(wz3),
                      "+v"(wz4), "+v"(wz5), "+v"(wz6), "+v"(wz7));
    asm volatile("" : "+v"(wn0), "+v"(wn1), "+v"(wn2), "+v"(wn3),
                      "+v"(wn4), "+v"(wn5), "+v"(wn6), "+v"(wn7));

    const float wih_r = Wih[j];           const float bih_r = bih[j];
    const float wih_z = Wih[j + HH];      const float bih_z = bih[j + HH];
    const float wih_n = Wih[j + 2 * HH];  const float bih_n = bih[j + 2 * HH];
    const float bhh_r = bhh[j];
    const float bhh_z = bhh[j + HH];
    const float bhh_n = bhh[j + 2 * HH];

    float hp = h_prev[(d * BB + b) * HH + j];   // own h, carried in register
    if (q == 0) hbuf[0][j + ((j >> 5) << 2)] = hp;
    __syncthreads();

    int p = 0;
    for (int c = 0; c < CC; ++c) {
        for (int ts = 0; ts < SS; ++ts) {
            const int tt = d ? (SS - 1 - ts) : ts;
            const float xv = xs[tt * CC + c];   // all-lane broadcast read

            const vf4* h4 = reinterpret_cast<const vf4*>(&hbuf[p][q * 36]);
            vf4 ra0 = {0.f,0.f,0.f,0.f}, ra1 = {0.f,0.f,0.f,0.f};
            vf4 za0 = {0.f,0.f,0.f,0.f}, za1 = {0.f,0.f,0.f,0.f};
            vf4 na0 = {0.f,0.f,0.f,0.f}, na1 = {0.f,0.f,0.f,0.f};
#define MAC2(i0, i1) { \
            const vf4 h0 = h4[i0], h1 = h4[i1]; \
            ra0 = __builtin_elementwise_fma(wr##i0, h0, ra0); \
            za0 = __builtin_elementwise_fma(wz##i0, h0, za0); \
            na0 = __builtin_elementwise_fma(wn##i0, h0, na0); \
            ra1 = __builtin_elementwise_fma(wr##i1, h1, ra1); \
            za1 = __builtin_elementwise_fma(wz##i1, h1, za1); \
            na1 = __builtin_elementwise_fma(wn##i1, h1, na1); }
            MAC2(0, 1) MAC2(2, 3) MAC2(4, 5) MAC2(6, 7)
#undef MAC2
            const vf4 rv = ra0 + ra1;
            const vf4 zv = za0 + za1;
            const vf4 nv = na0 + na1;
            float sr = (rv.x + rv.y) + (rv.z + rv.w);
            float sz = (zv.x + zv.y) + (zv.z + zv.w);
            float sn = (nv.x + nv.y) + (nv.z + nv.w);
            sr += __shfl_xor(sr, 1);  sr += __shfl_xor(sr, 2);
            sz += __shfl_xor(sz, 1);  sz += __shfl_xor(sz, 2);
            sn += __shfl_xor(sn, 1);  sn += __shfl_xor(sn, 2);

            const float gh_r = sr + bhh_r;
            const float gh_z = sz + bhh_z;
            const float gh_n = sn + bhh_n;
            const float gi_r = fmaf(xv, wih_r, bih_r);
            const float gi_z = fmaf(xv, wih_z, bih_z);
            const float gi_n = fmaf(xv, wih_n, bih_n);

            const float r = sigmoidf_(gi_r + gh_r);
            const float z = sigmoidf_(gi_z + gh_z);
            const float n = tanh_fast_(fmaf(r, gh_n, gi_n));
            const float hn = fmaf(z, hp - n, n);      // (1-z)*n + z*h
            hp = hn;                                  // all 4 lanes keep it

            if (q == 0) hbuf[p ^ 1][j + ((j >> 5) << 2)] = hn;
            __syncthreads();                          // single barrier per step
            p ^= 1;
        }
        if (q == 0) {
            hsnap[(((size_t)d * CC + c) * BB + b) * HH + j] = hp;
        }
    }
}

// One block (= one wave of 64 threads) per (c,b): FC + ReLU + softmax over O=64.
__global__ __launch_bounds__(64) void fc_softmax_kernel(
    const float* __restrict__ hsnap,   // (2, C, B, H)
    const float* __restrict__ W_fc,    // (O, 2H)
    const float* __restrict__ b_fc,    // (O,)
    float* __restrict__ out)           // (B, C, O)
{
    const int cb = blockIdx.x;         // c * B + b
    const int c  = cb >> 5;
    const int b  = cb & 31;
    const int o  = threadIdx.x;        // 0..63

    __shared__ float feat[2 * HH];     // [hf, hb]
    #pragma unroll
    for (int i = 0; i < 4; ++i) {
        const int idx = i * 64 + o;            // 0..255
        const int dd  = idx >> 7;              // 0: hf, 1: hb
        const int jj  = idx & (HH - 1);
        feat[idx] = hsnap[(((size_t)dd * CC + c) * BB + b) * HH + jj];
    }
    __syncthreads();

    float acc = 0.f;
    const float4* wrow = reinterpret_cast<const float4*>(W_fc + o * 2 * HH);
    const float4* f4   = reinterpret_cast<const float4*>(feat);
    #pragma unroll
    for (int k = 0; k < 64; ++k) {
        const float4 wv = wrow[k];
        const float4 fv = f4[k];
        acc = fmaf(wv.x, fv.x, acc);
        acc = fmaf(wv.y, fv.y, acc);
        acc = fmaf(wv.z, fv.z, acc);
        acc = fmaf(wv.w, fv.w, acc);
    }
    float v = fmaxf(acc + b_fc[o], 0.0f);

    float m = v;
    #pragma unroll
    for (int off = 32; off; off >>= 1) m = fmaxf(m, __shfl_xor(m, off));
    const float e = __expf(v - m);
    float ssum = e;
    #pragma unroll
    for (int off = 32; off; off >>= 1) ssum += __shfl_xor(ssum, off);

    out[((size_t)b * CC + c) * OO + o] = e / ssum;
}

extern "C" void kernel_launch(void* const* d_in, const int* in_sizes, int n_in,
                              void* d_out, int out_size, void* d_ws, size_t ws_size,
                              hipStream_t stream) {
    const float* x      = (const float*)d_in[0];
    const float* h_prev = (const float*)d_in[1];
    const float* Wih_f  = (const float*)d_in[2];
    const float* Whh_f  = (const float*)d_in[3];
    const float* bih_f  = (const float*)d_in[4];
    const float* bhh_f  = (const float*)d_in[5];
    const float* Wih_b  = (const float*)d_in[6];
    const float* Whh_b  = (const float*)d_in[7];
    const float* bih_b  = (const float*)d_in[8];
    const float* bhh_b  = (const float*)d_in[9];
    const float* W_fc   = (const float*)d_in[10];
    const float* b_fc   = (const float*)d_in[11];
    float* out   = (float*)d_out;
    float* hsnap = (float*)d_ws;   // 2*C*B*H*4 = 4 MiB of scratch

    gru_chain_kernel<<<64, 512, 0, stream>>>(x, h_prev, Wih_f, Whh_f, bih_f, bhh_f,
                                             Wih_b, Whh_b, bih_b, bhh_b, hsnap);
    fc_softmax_kernel<<<CC * BB, 64, 0, stream>>>(hsnap, W_fc, b_fc, out);
}

// Round 5
// 9348.026 us; speedup vs baseline: 1.6492x; 1.1646x over previous
//
#include <hip/hip_runtime.h>
#include <hip/hip_bf16.h>

#define BB 32
#define SS 128
#define CC 128
#define HH 128
#define OO 64

typedef float vf4 __attribute__((ext_vector_type(4)));

__device__ __forceinline__ float sigmoidf_(float x) {
    return 1.0f / (1.0f + __expf(-x));
}
__device__ __forceinline__ float tanh_fast_(float x) {
    return 1.0f - 2.0f / (__expf(2.0f * x) + 1.0f);  // |x| small here, no overflow
}

// Quad butterfly add on the VALU pipe (DPP quad_perm), replacing ds_swizzle
// shuffles. 0xB1 = [1,0,3,2] (xor1), 0x4E = [2,3,0,1] (xor2).
template <int CTRL>
__device__ __forceinline__ float dpp_add(float v) {
    int m = __builtin_amdgcn_update_dpp(0, __builtin_bit_cast(int, v),
                                        CTRL, 0xF, 0xF, true);
    return v + __builtin_bit_cast(float, m);
}

// One workgroup per (direction, batch). 512 threads = 8 waves.
// Thread (j = t>>2, q = t&3) computes gate rows j (r), j+128 (z), j+256 (n)
// over quarter q (32 floats) of the 128-wide dot. The 4 q-lanes of one j sit
// in one QUAD -> partial sums combined with 2 DPP quad_perm adds (VALU pipe,
// no LDS). All 4 lanes end with exact full sums, so every lane maintains hp.
// amdgpu_waves_per_eu(2,2) pins the compiler's occupancy target to 2
// waves/EU -> 256-VGPR budget, so the 96 weight floats stay arch-resident
// (rounds 2-4: allocator targeted 4 waves/EU from the LDS bound, capped at
// 128 VGPRs, and AGPR-shuffled the weights every step).
__global__
__attribute__((amdgpu_flat_work_group_size(512, 512), amdgpu_waves_per_eu(2, 2)))
void gru_chain_kernel(
    const float* __restrict__ x,       // (B,S,C)
    const float* __restrict__ h_prev,  // (2,B,H)
    const float* __restrict__ Wih_f, const float* __restrict__ Whh_f,
    const float* __restrict__ bih_f, const float* __restrict__ bhh_f,
    const float* __restrict__ Wih_b, const float* __restrict__ Whh_b,
    const float* __restrict__ bih_b, const float* __restrict__ bhh_b,
    float* __restrict__ hsnap)         // (2, C, B, H) column-end snapshots
{
    const int wg = blockIdx.x;
    const int d  = wg >> 5;        // 0 = forward, 1 = backward
    const int b  = wg & 31;
    const int t  = threadIdx.x;    // 0..511
    const int j  = t >> 2;         // hidden index 0..127
    const int q  = t & 3;          // quarter of the dot

    const float* __restrict__ Wih = d ? Wih_b : Wih_f;
    const float* __restrict__ Whh = d ? Whh_b : Whh_f;
    const float* __restrict__ bih = d ? bih_b : bih_f;
    const float* __restrict__ bhh = d ? bhh_b : bhh_f;

    __shared__ float xs[SS * CC];      // 64KB, x[b] slice (S,C) layout
    __shared__ float hbuf[2][144];     // quarter q at float-offset q*36 (bank skew)

    // stage x[b] (16384 contiguous floats) into LDS, coalesced float4
    {
        const float4* xb4 = reinterpret_cast<const float4*>(x + (size_t)b * SS * CC);
        float4* xs4 = reinterpret_cast<float4*>(xs);
        #pragma unroll
        for (int i = 0; i < 8; ++i) xs4[t + i * 512] = xb4[t + i * 512];
    }

    // 24 NAMED vf4 weight registers (96 VGPRs): rows j, j+128, j+256, quarter q
    const vf4* pr = reinterpret_cast<const vf4*>(Whh + (j          ) * HH + q * 32);
    const vf4* pz = reinterpret_cast<const vf4*>(Whh + (j +     HH ) * HH + q * 32);
    const vf4* pn = reinterpret_cast<const vf4*>(Whh + (j + 2 * HH ) * HH + q * 32);
    vf4 wr0 = pr[0], wr1 = pr[1], wr2 = pr[2], wr3 = pr[3],
        wr4 = pr[4], wr5 = pr[5], wr6 = pr[6], wr7 = pr[7];
    vf4 wz0 = pz[0], wz1 = pz[1], wz2 = pz[2], wz3 = pz[3],
        wz4 = pz[4], wz5 = pz[5], wz6 = pz[6], wz7 = pz[7];
    vf4 wn0 = pn[0], wn1 = pn[1], wn2 = pn[2], wn3 = pn[3],
        wn4 = pn[4], wn5 = pn[5], wn6 = pn[6], wn7 = pn[7];

    const float wih_r = Wih[j];           const float bih_r = bih[j];
    const float wih_z = Wih[j + HH];      const float bih_z = bih[j + HH];
    const float wih_n = Wih[j + 2 * HH];  const float bih_n = bih[j + 2 * HH];
    const float bhh_r = bhh[j];
    const float bhh_z = bhh[j + HH];
    const float bhh_n = bhh[j + 2 * HH];

    float hp = h_prev[(d * BB + b) * HH + j];   // own h, in register (all 4 lanes)
    const int hidx = ((j >> 5) * 36) + (j & 31); // skewed LDS slot for h[j]
    if (q == 0) hbuf[0][hidx] = hp;
    __syncthreads();

    // One GRU step: read h from hbuf[SRC], write new h to hbuf[DST].
#define GSTEP(SRC, DST, TSS)                                                  \
    {                                                                         \
        const int tt = d ? (SS - 1 - (TSS)) : (TSS);                          \
        const float xv = xs[tt * CC + c];       /* uniform broadcast read */  \
        const vf4* h4 = reinterpret_cast<const vf4*>(&hbuf[SRC][q * 36]);     \
        vf4 hv = h4[0];                                                       \
        vf4 ar = wr0 * hv, az = wz0 * hv, an = wn0 * hv;                      \
        hv = h4[1];                                                           \
        ar = __builtin_elementwise_fma(wr1, hv, ar);                          \
        az = __builtin_elementwise_fma(wz1, hv, az);                          \
        an = __builtin_elementwise_fma(wn1, hv, an);                          \
        hv = h4[2];                                                           \
        ar = __builtin_elementwise_fma(wr2, hv, ar);                          \
        az = __builtin_elementwise_fma(wz2, hv, az);                          \
        an = __builtin_elementwise_fma(wn2, hv, an);                          \
        hv = h4[3];                                                           \
        ar = __builtin_elementwise_fma(wr3, hv, ar);                          \
        az = __builtin_elementwise_fma(wz3, hv, az);                          \
        an = __builtin_elementwise_fma(wn3, hv, an);                          \
        hv = h4[4];                                                           \
        ar = __builtin_elementwise_fma(wr4, hv, ar);                          \
        az = __builtin_elementwise_fma(wz4, hv, az);                          \
        an = __builtin_elementwise_fma(wn4, hv, an);                          \
        hv = h4[5];                                                           \
        ar = __builtin_elementwise_fma(wr5, hv, ar);                          \
        az = __builtin_elementwise_fma(wz5, hv, az);                          \
        an = __builtin_elementwise_fma(wn5, hv, an);                          \
        hv = h4[6];                                                           \
        ar = __builtin_elementwise_fma(wr6, hv, ar);                          \
        az = __builtin_elementwise_fma(wz6, hv, az);                          \
        an = __builtin_elementwise_fma(wn6, hv, an);                          \
        hv = h4[7];                                                           \
        ar = __builtin_elementwise_fma(wr7, hv, ar);                          \
        az = __builtin_elementwise_fma(wz7, hv, az);                          \
        an = __builtin_elementwise_fma(wn7, hv, an);                          \
        float sr = (ar.x + ar.y) + (ar.z + ar.w);                             \
        float sz = (az.x + az.y) + (az.z + az.w);                             \
        float sn = (an.x + an.y) + (an.z + an.w);                             \
        sr = dpp_add<0xB1>(sr); sr = dpp_add<0x4E>(sr);                       \
        sz = dpp_add<0xB1>(sz); sz = dpp_add<0x4E>(sz);                       \
        sn = dpp_add<0xB1>(sn); sn = dpp_add<0x4E>(sn);                       \
        const float gh_r = sr + bhh_r;                                        \
        const float gh_z = sz + bhh_z;                                        \
        const float gh_n = sn + bhh_n;                                        \
        const float gi_r = fmaf(xv, wih_r, bih_r);                            \
        const float gi_z = fmaf(xv, wih_z, bih_z);                            \
        const float gi_n = fmaf(xv, wih_n, bih_n);                            \
        const float r = sigmoidf_(gi_r + gh_r);                               \
        const float z = sigmoidf_(gi_z + gh_z);                               \
        const float n = tanh_fast_(fmaf(r, gh_n, gi_n));                      \
        hp = fmaf(z, hp - n, n);               /* (1-z)*n + z*h */            \
        if (q == 0) hbuf[DST][hidx] = hp;                                     \
        __syncthreads();                                                      \
    }

    for (int c = 0; c < CC; ++c) {
        for (int ts = 0; ts < SS; ts += 2) {
            GSTEP(0, 1, ts)        // h: buf0 -> buf1
            GSTEP(1, 0, ts + 1)    // h: buf1 -> buf0
        }
        if (q == 0) {
            hsnap[(((size_t)d * CC + c) * BB + b) * HH + j] = hp;
        }
    }
#undef GSTEP
}

// One block (= one wave of 64 threads) per (c,b): FC + ReLU + softmax over O=64.
__global__ __launch_bounds__(64) void fc_softmax_kernel(
    const float* __restrict__ hsnap,   // (2, C, B, H)
    const float* __restrict__ W_fc,    // (O, 2H)
    const float* __restrict__ b_fc,    // (O,)
    float* __restrict__ out)           // (B, C, O)
{
    const int cb = blockIdx.x;         // c * B + b
    const int c  = cb >> 5;
    const int b  = cb & 31;
    const int o  = threadIdx.x;        // 0..63

    __shared__ float feat[2 * HH];     // [hf, hb]
    #pragma unroll
    for (int i = 0; i < 4; ++i) {
        const int idx = i * 64 + o;            // 0..255
        const int dd  = idx >> 7;              // 0: hf, 1: hb
        const int jj  = idx & (HH - 1);
        feat[idx] = hsnap[(((size_t)dd * CC + c) * BB + b) * HH + jj];
    }
    __syncthreads();

    float acc = 0.f;
    const float4* wrow = reinterpret_cast<const float4*>(W_fc + o * 2 * HH);
    const float4* f4   = reinterpret_cast<const float4*>(feat);
    #pragma unroll
    for (int k = 0; k < 64; ++k) {
        const float4 wv = wrow[k];
        const float4 fv = f4[k];
        acc = fmaf(wv.x, fv.x, acc);
        acc = fmaf(wv.y, fv.y, acc);
        acc = fmaf(wv.z, fv.z, acc);
        acc = fmaf(wv.w, fv.w, acc);
    }
    float v = fmaxf(acc + b_fc[o], 0.0f);

    float m = v;
    #pragma unroll
    for (int off = 32; off; off >>= 1) m = fmaxf(m, __shfl_xor(m, off));
    const float e = __expf(v - m);
    float ssum = e;
    #pragma unroll
    for (int off = 32; off; off >>= 1) ssum += __shfl_xor(ssum, off);

    out[((size_t)b * CC + c) * OO + o] = e / ssum;
}

extern "C" void kernel_launch(void* const* d_in, const int* in_sizes, int n_in,
                              void* d_out, int out_size, void* d_ws, size_t ws_size,
                              hipStream_t stream) {
    const float* x      = (const float*)d_in[0];
    const float* h_prev = (const float*)d_in[1];
    const float* Wih_f  = (const float*)d_in[2];
    const float* Whh_f  = (const float*)d_in[3];
    const float* bih_f  = (const float*)d_in[4];
    const float* bhh_f  = (const float*)d_in[5];
    const float* Wih_b  = (const float*)d_in[6];
    const float* Whh_b  = (const float*)d_in[7];
    const float* bih_b  = (const float*)d_in[8];
    const float* bhh_b  = (const float*)d_in[9];
    const float* W_fc   = (const float*)d_in[10];
    const float* b_fc   = (const float*)d_in[11];
    float* out   = (float*)d_out;
    float* hsnap = (float*)d_ws;   // 2*C*B*H*4 = 4 MiB of scratch

    gru_chain_kernel<<<64, 512, 0, stream>>>(x, h_prev, Wih_f, Whh_f, bih_f, bhh_f,
                                             Wih_b, Whh_b, bih_b, bhh_b, hsnap);
    fc_softmax_kernel<<<CC * BB, 64, 0, stream>>>(hsnap, W_fc, b_fc, out);
}